// Round 12
// baseline (93.087 us; speedup 1.0000x reference)
//
#include <hip/hip_runtime.h>
#include <hip/hip_fp16.h>

// Separable 3D Gaussian blur (sigma=1, truncate=3 -> 7 taps), SAME zero padding.
// (N=2, D=160, H=160, W=160, C=4) float32 == float4 over C.
// Round 12 = R11 structure with fp16 LDS tiles + packed-half2 blur math:
//  - raw & wb stored as f16x4 (uint2): halves all LDS bytes; W-reads become
//    5x uint4, H-reads lane-contiguous b64 (conflict-free).
//  - W/H/D blur in __hfma2 packed math (14 pk-ops per blur7 vs 40 f32);
//    D-rings are uint2 (28 VGPR vs 56).
//  - accuracy: R9 measured fp16-wb-only at absmax 3.9e-3 (thr 1.7e-2);
//    full-f16 path predicted ~4-8e-3.
// Unchanged from R11: tile 16x32, CHUNK=10, 1600 blocks, XCD-chunked swizzle,
// register prefetch 1 slice ahead, 2 lgkmcnt-only barriers, launch_bounds(256,4).

#define THT 16
#define TWT 32
#define CHUNK 10
#define DIM 160
#define SLICE (DIM * DIM)
#define RAWN (22 * 38)
#define NBLK 1600          // 2 * 10 * 5 * 16 = 8 XCDs x 200

#define W0f 0.004433048f
#define W1f 0.054005582f
#define W2f 0.242036229f
#define W3f 0.399050300f

__device__ __forceinline__ __half2 h2lo(uint2 u) { return *reinterpret_cast<const __half2*>(&u.x); }
__device__ __forceinline__ __half2 h2hi(uint2 u) { return *reinterpret_cast<const __half2*>(&u.y); }
__device__ __forceinline__ unsigned h2u(__half2 h) { return *reinterpret_cast<const unsigned*>(&h); }

__device__ __forceinline__ uint2 pack2(float4 v) {
    __half2 a = __floats2half2_rn(v.x, v.y);
    __half2 b = __floats2half2_rn(v.z, v.w);
    uint2 r; r.x = h2u(a); r.y = h2u(b); return r;
}
__device__ __forceinline__ float4 unpack2(uint2 u) {
    float2 a = __half22float2(h2lo(u));
    float2 b = __half22float2(h2hi(u));
    return make_float4(a.x, a.y, b.x, b.y);
}

// packed blur7: per half2 = 3 hadd2 + 1 hmul2 + 3 hfma2
__device__ __forceinline__ uint2 blur7h(uint2 a0, uint2 a1, uint2 a2, uint2 a3,
                                        uint2 a4, uint2 a5, uint2 a6,
                                        __half2 w0, __half2 w1, __half2 w2, __half2 w3) {
    __half2 lo = __hmul2(w3, h2lo(a3));
    lo = __hfma2(w0, __hadd2(h2lo(a0), h2lo(a6)), lo);
    lo = __hfma2(w1, __hadd2(h2lo(a1), h2lo(a5)), lo);
    lo = __hfma2(w2, __hadd2(h2lo(a2), h2lo(a4)), lo);
    __half2 hi = __hmul2(w3, h2hi(a3));
    hi = __hfma2(w0, __hadd2(h2hi(a0), h2hi(a6)), hi);
    hi = __hfma2(w1, __hadd2(h2hi(a1), h2hi(a5)), hi);
    hi = __hfma2(w2, __hadd2(h2hi(a2), h2hi(a4)), hi);
    uint2 r; r.x = h2u(lo); r.y = h2u(hi); return r;
}

// Workgroup barrier with LDS visibility but NO vmcnt(0) drain -> prefetched
// global loads stay in flight across it.
__device__ __forceinline__ void lds_barrier() {
    asm volatile("s_waitcnt lgkmcnt(0)" ::: "memory");
    __builtin_amdgcn_s_barrier();
}

__global__ __launch_bounds__(256, 4)
void gauss3d_fused(const float4* __restrict__ in, float4* __restrict__ out) {
    // XCD-chunked bijective swizzle: 1600 = 8 * 200 exactly.
    int work = (blockIdx.x & 7) * (NBLK / 8) + (blockIdx.x >> 3);
    const int tw    = work % (DIM / TWT);   work /= (DIM / TWT);   // 5
    const int th    = work % (DIM / THT);   work /= (DIM / THT);   // 10
    const int chunk = work % (DIM / CHUNK); work /= (DIM / CHUNK); // 16
    const int n     = work;                                        // 2

    const int h0 = th * THT;
    const int w0 = tw * TWT;
    const int d0 = chunk * CHUNK;

    __shared__ uint2 raw[22][40];   // halo 22(H) x 38(W) f16x4; pad 40 (16B-aligned rows)
    __shared__ uint2 wb[22][34];    // W-blurred 22 x 32 f16x4; pad 34 (16B-aligned rows)

    const int tid = threadIdx.x;
    const size_t nbase = (size_t)n * DIM * SLICE;
    const float4 z = make_float4(0.f, 0.f, 0.f, 0.f);

    const __half2 w0h = __float2half2_rn(W0f);
    const __half2 w1h = __float2half2_rn(W1f);
    const __half2 w2h = __float2half2_rn(W2f);
    const __half2 w3h = __float2half2_rn(W3f);
    const uint2 zh = make_uint2(0u, 0u);

    // ---- stage constants: 836 halo f4 over 256 threads (<=4 slots) ----
    int  soff[4], rbidx[4];
    bool sok[4];
    #pragma unroll
    for (int s = 0; s < 4; ++s) {
        const int i = tid + 256 * s;
        const bool has = (i < RAWN);
        const int rr = has ? (i / 38) : 0, cc = has ? (i % 38) : 0;
        const int gh = h0 + rr - 3, gw = w0 + cc - 3;
        const bool ok = has && gh >= 0 && gh < DIM && gw >= 0 && gw < DIM;
        soff[s]  = ok ? (gh * DIM + gw) : 0;
        sok[s]   = ok;
        rbidx[s] = rr * 40 + cc;
    }
    const bool shas3 = (tid + 768 < RAWN);

    // ---- W-blur workers: 176 = 22 rows x 8 groups of 4 cols ----
    const bool isW = (tid < 176);
    const int wr  = tid >> 3;        // 0..21
    const int wc0 = (tid & 7) * 4;   // 0,4,...,28 (even -> 16B-aligned uint4)

    // ---- H-blur: 256 threads = 8 H-pairs x 32 cols ----
    const int hp = tid >> 5;         // 0..7 -> output rows 2hp, 2hp+1
    const int lw = tid & 31;         // 0..31

    float4 pf0, pf1, pf2, pf3;
    uint2 a0 = zh, a1 = zh, a2 = zh, a3 = zh, a4 = zh, a5 = zh, a6 = zh;
    uint2 b0 = zh, b1 = zh, b2 = zh, b3 = zh, b4 = zh, b5 = zh, b6 = zh;

#define PREFETCH(DSL)                                                        \
    do {                                                                     \
        const int _d = (DSL);                                                \
        const bool _inr = (_d >= 0) && (_d < DIM);                           \
        const float4* _s = in + nbase + (size_t)(_inr ? _d : 0) * SLICE;     \
        pf0 = (_inr && sok[0]) ? _s[soff[0]] : z;                            \
        pf1 = (_inr && sok[1]) ? _s[soff[1]] : z;                            \
        pf2 = (_inr && sok[2]) ? _s[soff[2]] : z;                            \
        pf3 = (_inr && sok[3]) ? _s[soff[3]] : z;                            \
    } while (0)

    PREFETCH(d0 - 3);

    for (int din = d0 - 3; din <= d0 + CHUNK + 2; ++din) {
        // 1) commit prefetched slice into raw as f16x4 (b64 writes)
        {
            uint2* rb = &raw[0][0];
            rb[rbidx[0]] = pack2(pf0);
            rb[rbidx[1]] = pack2(pf1);
            rb[rbidx[2]] = pack2(pf2);
            if (shas3) rb[rbidx[3]] = pack2(pf3);
        }

        // 2) issue next slice's loads; stay in flight across both barriers
        PREFETCH(din + 1);

        lds_barrier();  // A: raw visible; prev H-blur reads of wb drained

        // 3) W-blur: 176 workers; 5x uint4 reads -> 4 packed outputs
        if (isW) {
            const uint4* rp = reinterpret_cast<const uint4*>(&raw[wr][wc0]);
            uint4 q0 = rp[0], q1 = rp[1], q2 = rp[2], q3 = rp[3], q4 = rp[4];
            uint2 s0 = make_uint2(q0.x, q0.y), s1 = make_uint2(q0.z, q0.w);
            uint2 s2 = make_uint2(q1.x, q1.y), s3 = make_uint2(q1.z, q1.w);
            uint2 s4 = make_uint2(q2.x, q2.y), s5 = make_uint2(q2.z, q2.w);
            uint2 s6 = make_uint2(q3.x, q3.y), s7 = make_uint2(q3.z, q3.w);
            uint2 s8 = make_uint2(q4.x, q4.y), s9 = make_uint2(q4.z, q4.w);
            uint2 o0 = blur7h(s0, s1, s2, s3, s4, s5, s6, w0h, w1h, w2h, w3h);
            uint2 o1 = blur7h(s1, s2, s3, s4, s5, s6, s7, w0h, w1h, w2h, w3h);
            uint2 o2 = blur7h(s2, s3, s4, s5, s6, s7, s8, w0h, w1h, w2h, w3h);
            uint2 o3 = blur7h(s3, s4, s5, s6, s7, s8, s9, w0h, w1h, w2h, w3h);
            uint4* wp = reinterpret_cast<uint4*>(&wb[wr][wc0]);
            wp[0] = make_uint4(o0.x, o0.y, o1.x, o1.y);
            wp[1] = make_uint4(o2.x, o2.y, o3.x, o3.y);
        }

        lds_barrier();  // B: wb visible; raw reads drained (next top rewrites)

        // 4) H-blur pair (lane-contiguous b64 reads, conflict-free)
        {
            uint2 c0 = wb[2 * hp + 0][lw];
            uint2 c1 = wb[2 * hp + 1][lw];
            uint2 c2 = wb[2 * hp + 2][lw];
            uint2 c3 = wb[2 * hp + 3][lw];
            uint2 c4 = wb[2 * hp + 4][lw];
            uint2 c5 = wb[2 * hp + 5][lw];
            uint2 c6 = wb[2 * hp + 6][lw];
            uint2 c7 = wb[2 * hp + 7][lw];
            uint2 va = blur7h(c0, c1, c2, c3, c4, c5, c6, w0h, w1h, w2h, w3h);
            uint2 vb = blur7h(c1, c2, c3, c4, c5, c6, c7, w0h, w1h, w2h, w3h);
            a0 = a1; a1 = a2; a2 = a3; a3 = a4; a4 = a5; a5 = a6; a6 = va;
            b0 = b1; b1 = b2; b2 = b3; b3 = b4; b4 = b5; b5 = b6; b6 = vb;
        }

        const int dout = din - 3;
        if (dout >= d0) {   // dout < d0+CHUNK by loop bound
            uint2 oa = blur7h(a0, a1, a2, a3, a4, a5, a6, w0h, w1h, w2h, w3h);
            uint2 ob = blur7h(b0, b1, b2, b3, b4, b5, b6, w0h, w1h, w2h, w3h);
            const size_t base = nbase + (size_t)dout * SLICE;
            out[base + (size_t)(h0 + 2 * hp + 0) * DIM + (w0 + lw)] = unpack2(oa);
            out[base + (size_t)(h0 + 2 * hp + 1) * DIM + (w0 + lw)] = unpack2(ob);
        }
    }
#undef PREFETCH
}

extern "C" void kernel_launch(void* const* d_in, const int* in_sizes, int n_in,
                              void* d_out, int out_size, void* d_ws, size_t ws_size,
                              hipStream_t stream) {
    const float4* in = (const float4*)d_in[0];
    float4* out = (float4*)d_out;
    gauss3d_fused<<<NBLK, 256, 0, stream>>>(in, out);
}